// Round 5
// baseline (316.059 us; speedup 1.0000x reference)
//
#include <hip/hip_runtime.h>
#include <hip/hip_bf16.h>
#include <stdint.h>

// Shapes (fixed by the problem)
#define BATCH 2048
#define NHID  512
#define KMAIN 65792          // 257*256 = 1028*64  (k = i*256 + j, j<256)
#define KPAD  66112          // KMAIN + 320 = 1033*64 (tail: k-KMAIN = i, j=256 col)
#define NSTEP 1033
#define TAILSTEP 1028        // KMAIN/64
#define SPLITS 12
#define PERSPLIT 87          // ceil(1033/12); last split gets 76 steps
#define AW 320               // a_tab row width (256 vals, 1.0 at 256, zeros to 320)
#define CW 256               // c_tab row width

typedef __attribute__((ext_vector_type(8))) short short8;
typedef __attribute__((ext_vector_type(4))) short short4v;
typedef __attribute__((ext_vector_type(4))) float f32x4;

#define AS1 __attribute__((address_space(1)))
#define AS3 __attribute__((address_space(3)))

__device__ __forceinline__ unsigned short f2bf(float f) {
    union { float f; unsigned int u; } v; v.f = f;
    unsigned int r = v.u + 0x7FFFu + ((v.u >> 16) & 1u);
    return (unsigned short)(r >> 16);
}
__device__ __forceinline__ unsigned short f2bf_fast(float f) {
    __hip_bfloat16 h = __float2bfloat16(f);            // RTNE
    return *reinterpret_cast<unsigned short*>(&h);
}
__device__ __forceinline__ float bf2f(unsigned short u) {
    union { unsigned int i; float f; } v; v.i = ((unsigned int)u) << 16;
    return v.f;
}

// W1 source row for permuted k (or -1 for zero-pad)
__device__ __forceinline__ int w1_src_row(int k) {
    if (k < KMAIN) return (k >> 8) * 257 + (k & 255);   // i*257 + j
    int i = k - KMAIN;
    return (i < 257) ? (i * 257 + 256) : -1;             // (i, j=256) column
}

// ---------------------------------------------------------------------------
// Merged prep: W1t (permuted transpose+cvt), W2t (transpose+cvt),
// a_tab [2048][320] bf16, c_tab [2048][256] bf16.  One launch.
// ---------------------------------------------------------------------------
__global__ __launch_bounds__(256) void prep_kernel(
        const float* __restrict__ inp1, const float* __restrict__ inp2,
        const float* __restrict__ W1, const float* __restrict__ W2,
        unsigned short* __restrict__ W1t, unsigned short* __restrict__ W2t,
        unsigned short* __restrict__ a_tab, unsigned short* __restrict__ c_tab) {
    __shared__ float T[64][65];
    int b = blockIdx.x;
    int t = threadIdx.x;

    if (b < 8264 + 64) {
        const float* src; unsigned short* dst; int k0, n0, Kpad; bool perm;
        if (b < 8264) {
            int kt = b % 1033, nt = b / 1033;
            src = W1; dst = W1t; k0 = kt * 64; n0 = nt * 64; Kpad = KPAD; perm = true;
        } else {
            int bb = b - 8264;
            int kt = bb & 7, nt = bb >> 3;
            src = W2; dst = W2t; k0 = kt * 64; n0 = nt * 64; Kpad = 512; perm = false;
        }
        int nn = t & 63, kk0 = t >> 6;
#pragma unroll
        for (int it = 0; it < 16; ++it) {
            int kk = it * 4 + kk0;
            int k = k0 + kk;
            int row = perm ? w1_src_row(k) : k;
            float v = (row >= 0) ? src[(long)row * NHID + n0 + nn] : 0.f;
            T[kk][nn] = v;
        }
        __syncthreads();
#pragma unroll
        for (int it = 0; it < 2; ++it) {
            int idx = it * 256 + t;
            int nl = idx >> 3, ch = idx & 7;
            short8 o;
#pragma unroll
            for (int e = 0; e < 8; ++e) o[e] = (short)f2bf(T[ch * 8 + e][nl]);
            *reinterpret_cast<short8*>(&dst[(long)(n0 + nl) * Kpad + k0 + ch * 8]) = o;
        }
    } else {
        int r0 = (b - 8328) * 32;
        for (int idx = t; idx < 32 * (AW / 8); idx += 256) {
            int r = idx / 40, ch = idx - r * 40;
            int m = r0 + r;
            short8 o;
#pragma unroll
            for (int e = 0; e < 8; ++e) {
                int i = ch * 8 + e;
                float v = (i < 256) ? inp1[m * 256 + i] : (i == 256 ? 1.0f : 0.0f);
                o[e] = (short)f2bf(v);
            }
            *reinterpret_cast<short8*>(&a_tab[m * AW + ch * 8]) = o;
        }
        for (int idx = t; idx < 32 * (CW / 8); idx += 256) {
            int r = idx >> 5, ch = idx & 31;
            int m = r0 + r;
            short8 o;
#pragma unroll
            for (int e = 0; e < 8; ++e) o[e] = (short)f2bf(inp2[m * 256 + ch * 8 + e]);
            *reinterpret_cast<short8*>(&c_tab[m * CW + ch * 8]) = o;
        }
    }
}

// ---------------------------------------------------------------------------
// Stage a [128 rows][64 k] bf16 tile into LDS via global_load_lds (16B),
// XOR swizzle via permuted per-lane source chunk.  256 threads.
// ---------------------------------------------------------------------------
__device__ __forceinline__ void stage_tile128(const unsigned short* __restrict__ g,
        long row0, long k0, long ld, unsigned short* lds) {
    int t = threadIdx.x;
    int wave = t >> 6, lane = t & 63;
    int rl = lane >> 3;
    int ch = (lane & 7) ^ rl;
    const unsigned short* src0 = g + (row0 + wave * 8 + rl) * ld + k0 + ch * 8;
#pragma unroll
    for (int r = 0; r < 4; ++r) {
        const unsigned short* src = src0 + (long)r * 32 * ld;
        unsigned short* dst = lds + (r * 32 + wave * 8) * 64;   // wave-uniform
        __builtin_amdgcn_global_load_lds((const AS1 unsigned int*)src,
                                         (AS3 unsigned int*)dst, 16, 0, 0);
    }
}

// Fragment read: logical (rowbase+(lane&15), k = kofs + (lane>>4)*8 .. +8)
__device__ __forceinline__ short8 read_frag(const unsigned short* lds,
        int rowbase, int kofs, int lane) {
    int row = rowbase + (lane & 15);
    int chunkL = (kofs >> 3) + (lane >> 4);
    int sw = chunkL ^ (row & 7);
    return *reinterpret_cast<const short8*>(&lds[row * 64 + sw * 8]);
}

// ---------------------------------------------------------------------------
// GEMM1: hacc += A(m-tile) @ W1t^T(n-tile), split-K via atomics.
// A generated in registers from A-source regs PREFETCHED ONE STEP AHEAD
// (loads issued before B staging; barrier drain completes them) -> the
// per-step A-gen is pure VALU with no memory waits.  B double-buffered in
// LDS, one barrier per step.  4 waves, wave wv owns rows [m0+wv*32,+32).
// grid = 16(M) * 4(N) * 12(S) = 768 blocks = 3/CU.
// ---------------------------------------------------------------------------
__global__ __launch_bounds__(256, 3) void gemm1_kernel(
        const unsigned short* __restrict__ a_tab,
        const unsigned short* __restrict__ c_tab,
        const unsigned short* __restrict__ W1t, float* __restrict__ hacc) {
    __shared__ unsigned short B_s[2][128 * 64];
    // T1: nwg = 768 divisible by 8 -> bijective XCD swizzle, m fastest
    int bid = (blockIdx.x & 7) * 96 + (blockIdx.x >> 3);
    int m0 = (bid & 15) * 128;
    int n0 = ((bid >> 4) & 3) * 128;
    int s  = bid >> 6;
    int st0 = s * PERSPLIT;
    int st1 = st0 + PERSPLIT; if (st1 > NSTEP) st1 = NSTEP;

    int lane = threadIdx.x & 63;
    int wv = threadIdx.x >> 6;
    int wrow = m0 + wv * 32;
    int rowA0 = wrow + (lane & 15);        // fm=0 fragment row
    int rowA1 = rowA0 + 16;                // fm=1 fragment row
    int kq = (lane >> 4) * 8;              // k quad offset within 32

    const unsigned short* c0 = c_tab + rowA0 * CW;
    const unsigned short* c1 = c_tab + rowA1 * CW;
    const unsigned short* at0 = a_tab + rowA0 * AW;
    const unsigned short* at1 = a_tab + rowA1 * AW;

    f32x4 acc[2][8];
#pragma unroll
    for (int a = 0; a < 2; ++a)
#pragma unroll
        for (int b = 0; b < 8; ++b) acc[a][b] = (f32x4){0.f, 0.f, 0.f, 0.f};

    // ---- prologue: prefetch A-source for st0 + stage B(st0) ----
    float avC0, avC1;
    short8 srcC[2][2];                     // [kk][fm]
    {
        int kb = st0 * 64;                 // st0 < TAILSTEP always (<=957)
        int i = kb >> 8;
        avC0 = bf2f(at0[i]);
        avC1 = bf2f(at1[i]);
        int j0 = (kb & 255) + kq;
        srcC[0][0] = *reinterpret_cast<const short8*>(&c0[j0]);
        srcC[0][1] = *reinterpret_cast<const short8*>(&c1[j0]);
        srcC[1][0] = *reinterpret_cast<const short8*>(&c0[j0 + 32]);
        srcC[1][1] = *reinterpret_cast<const short8*>(&c1[j0 + 32]);
    }
    stage_tile128(W1t, n0, (long)st0 * 64, KPAD, &B_s[0][0]);
    __syncthreads();
    int cur = 0;

    for (int st = st0; st < st1; ++st) {
        // ---- A fragments: pure VALU on prefetched registers ----
        short8 aF[2][2];
        if (st < TAILSTEP) {
#pragma unroll
            for (int kk = 0; kk < 2; ++kk) {
                short8 o0, o1;
#pragma unroll
                for (int e = 0; e < 8; ++e) {
                    o0[e] = (short)f2bf_fast(avC0 * bf2f((unsigned short)srcC[kk][0][e]));
                    o1[e] = (short)f2bf_fast(avC1 * bf2f((unsigned short)srcC[kk][1][e]));
                }
                aF[kk][0] = o0; aF[kk][1] = o1;
            }
        } else {
#pragma unroll
            for (int kk = 0; kk < 2; ++kk) {
                aF[kk][0] = srcC[kk][0];
                aF[kk][1] = srcC[kk][1];
            }
        }

        // ---- prefetch A-source for st+1 (ISSUED BEFORE B staging) ----
        if (st + 1 < st1) {
            int kb2 = (st + 1) * 64;
            if (st + 1 < TAILSTEP) {
                int i2 = kb2 >> 8;
                avC0 = bf2f(at0[i2]);
                avC1 = bf2f(at1[i2]);
                int j2 = (kb2 & 255) + kq;
                srcC[0][0] = *reinterpret_cast<const short8*>(&c0[j2]);
                srcC[0][1] = *reinterpret_cast<const short8*>(&c1[j2]);
                srcC[1][0] = *reinterpret_cast<const short8*>(&c0[j2 + 32]);
                srcC[1][1] = *reinterpret_cast<const short8*>(&c1[j2 + 32]);
            } else {
                int koff = kb2 - KMAIN + kq;
                srcC[0][0] = *reinterpret_cast<const short8*>(&at0[koff]);
                srcC[0][1] = *reinterpret_cast<const short8*>(&at1[koff]);
                srcC[1][0] = *reinterpret_cast<const short8*>(&at0[koff + 32]);
                srcC[1][1] = *reinterpret_cast<const short8*>(&at1[koff + 32]);
            }
            // ---- B staging for st+1 (vmcnt-after A-source loads) ----
            stage_tile128(W1t, n0, (long)(st + 1) * 64, KPAD, &B_s[cur ^ 1][0]);
        }

        // ---- B fragments from LDS + MFMA ----
#pragma unroll
        for (int kk = 0; kk < 2; ++kk) {
            short8 bF[8];
#pragma unroll
            for (int fn = 0; fn < 8; ++fn)
                bF[fn] = read_frag(&B_s[cur][0], fn * 16, kk * 32, lane);
#pragma unroll
            for (int fm = 0; fm < 2; ++fm)
#pragma unroll
                for (int fn = 0; fn < 8; ++fn)
                    acc[fm][fn] = __builtin_amdgcn_mfma_f32_16x16x32_bf16(
                        aF[kk][fm], bF[fn], acc[fm][fn], 0, 0, 0);
        }
        __syncthreads();                   // single structural drain per step
        cur ^= 1;
    }

    // epilogue: atomic split-K accumulate into f32 hacc (= d_out scratch)
    int cl = lane & 15;
    int r4 = (lane >> 4) * 4;
#pragma unroll
    for (int fm = 0; fm < 2; ++fm)
#pragma unroll
        for (int fn = 0; fn < 8; ++fn)
#pragma unroll
            for (int r = 0; r < 4; ++r) {
                int row = wrow + fm * 16 + r4 + r;
                int col = n0 + fn * 16 + cl;
                atomicAdd(&hacc[row * NHID + col], acc[fm][fn][r]);
            }
}

// h = bf16(relu(hacc + b1))
__global__ __launch_bounds__(256) void bias_relu_h_kernel(
        const float* __restrict__ hacc, const float* __restrict__ b1,
        unsigned short* __restrict__ h) {
    int idx = blockIdx.x * 256 + threadIdx.x;
    f32x4 v = ((const f32x4*)hacc)[idx];
    int col = (idx & 127) << 2;
    f32x4 bb = *(const f32x4*)(b1 + col);
    short4v o;
#pragma unroll
    for (int e = 0; e < 4; ++e) {
        float x = v[e] + bb[e];
        x = fmaxf(x, 0.f);
        o[e] = (short)f2bf(x);
    }
    ((short4v*)h)[idx] = o;
}

// ---------------------------------------------------------------------------
// GEMM2: out = relu(h @ W2 + b2).  M=2048,N=512,K=512.  grid 16x4.
// ---------------------------------------------------------------------------
__global__ __launch_bounds__(256) void gemm2_kernel(
        const unsigned short* __restrict__ h, const unsigned short* __restrict__ W2t,
        const float* __restrict__ b2, float* __restrict__ out) {
    __shared__ unsigned short A_s[128 * 64];
    __shared__ unsigned short B_s[128 * 64];
    int m0 = (blockIdx.x >> 2) * 128;
    int n0 = (blockIdx.x & 3) * 128;
    int lane = threadIdx.x & 63;
    int wv = threadIdx.x >> 6;
    int wm = (wv >> 1) * 64;
    int wn = (wv & 1) * 64;

    f32x4 acc[4][4];
#pragma unroll
    for (int a = 0; a < 4; ++a)
#pragma unroll
        for (int b = 0; b < 4; ++b) acc[a][b] = (f32x4){0.f, 0.f, 0.f, 0.f};

    for (int st = 0; st < 8; ++st) {
        int kbase = st * 64;
        __syncthreads();
        stage_tile128(h,   m0, kbase, NHID, A_s);
        stage_tile128(W2t, n0, kbase, NHID, B_s);
        __syncthreads();
#pragma unroll
        for (int kk = 0; kk < 2; ++kk) {
            short8 aF[4], bF[4];
#pragma unroll
            for (int fm = 0; fm < 4; ++fm) aF[fm] = read_frag(A_s, wm + fm * 16, kk * 32, lane);
#pragma unroll
            for (int fn = 0; fn < 4; ++fn) bF[fn] = read_frag(B_s, wn + fn * 16, kk * 32, lane);
#pragma unroll
            for (int fm = 0; fm < 4; ++fm)
#pragma unroll
                for (int fn = 0; fn < 4; ++fn)
                    acc[fm][fn] = __builtin_amdgcn_mfma_f32_16x16x32_bf16(
                        aF[fm], bF[fn], acc[fm][fn], 0, 0, 0);
        }
    }
    int cl = lane & 15;
    int r4 = (lane >> 4) * 4;
#pragma unroll
    for (int fm = 0; fm < 4; ++fm)
#pragma unroll
        for (int fn = 0; fn < 4; ++fn)
#pragma unroll
            for (int r = 0; r < 4; ++r) {
                int row = m0 + wm + fm * 16 + r4 + r;
                int col = n0 + wn + fn * 16 + cl;
                float x = acc[fm][fn][r] + b2[col];
                out[row * NHID + col] = fmaxf(x, 0.f);
            }
}

extern "C" void kernel_launch(void* const* d_in, const int* in_sizes, int n_in,
                              void* d_out, int out_size, void* d_ws, size_t ws_size,
                              hipStream_t stream) {
    const float* inp1 = (const float*)d_in[0];
    const float* inp2 = (const float*)d_in[1];
    const float* W1   = (const float*)d_in[2];
    const float* b1   = (const float*)d_in[3];
    const float* W2   = (const float*)d_in[4];
    const float* b2   = (const float*)d_in[5];
    float* out = (float*)d_out;

    // workspace layout (~72.5 MB)
    size_t off = 0;
    auto alloc = [&](size_t bytes) {
        void* p = (char*)d_ws + off;
        off += (bytes + 255) & ~(size_t)255;
        return p;
    };
    unsigned short* W1t   = (unsigned short*)alloc((size_t)NHID * KPAD * 2);
    unsigned short* W2t   = (unsigned short*)alloc((size_t)NHID * NHID * 2);
    unsigned short* h     = (unsigned short*)alloc((size_t)BATCH * NHID * 2);
    unsigned short* a_tab = (unsigned short*)alloc((size_t)BATCH * AW * 2);
    unsigned short* c_tab = (unsigned short*)alloc((size_t)BATCH * CW * 2);
    (void)ws_size; (void)in_sizes; (void)n_in; (void)out_size;

    // d_out doubles as the f32 split-K accumulator for h_pre
    hipMemsetAsync(d_out, 0, (size_t)BATCH * NHID * 4, stream);

    prep_kernel<<<8264 + 64 + 64, 256, 0, stream>>>(inp1, inp2, W1, W2,
                                                    W1t, W2t, a_tab, c_tab);

    gemm1_kernel<<<64 * SPLITS, 256, 0, stream>>>(a_tab, c_tab, W1t, (float*)d_out);
    bias_relu_h_kernel<<<(BATCH * NHID / 4) / 256, 256, 0, stream>>>((const float*)d_out, b1, h);
    gemm2_kernel<<<64, 256, 0, stream>>>(h, W2t, b2, out);
}

// Round 6
// 233.162 us; speedup vs baseline: 1.3555x; 1.3555x over previous
//
#include <hip/hip_runtime.h>
#include <hip/hip_bf16.h>
#include <stdint.h>

// Shapes (fixed by the problem)
#define BATCH 2048
#define NHID  512
#define KMAIN 65792          // 257*256 = 1028*64  (k = i*256 + j, j<256)
#define KPAD  66112          // KMAIN + 320 = 1033*64 (tail: k-KMAIN = i, j=256 col)
#define NSTEP 1033
#define SPLITS 8             // 8 main splits x 128 steps = steps [0,1024)
#define AW 320               // a_tab row width (256 vals, 1.0 at 256, zeros to 320)
#define CW 256               // c_tab row width

typedef __attribute__((ext_vector_type(8))) short short8;
typedef __attribute__((ext_vector_type(4))) short short4v;
typedef __attribute__((ext_vector_type(4))) float f32x4;

#define AS1 __attribute__((address_space(1)))
#define AS3 __attribute__((address_space(3)))

__device__ __forceinline__ unsigned short f2bf(float f) {
    union { float f; unsigned int u; } v; v.f = f;
    unsigned int r = v.u + 0x7FFFu + ((v.u >> 16) & 1u);
    return (unsigned short)(r >> 16);
}
__device__ __forceinline__ unsigned short f2bf_fast(float f) {
    __hip_bfloat16 h = __float2bfloat16(f);            // RTNE
    return *reinterpret_cast<unsigned short*>(&h);
}
__device__ __forceinline__ float bf2f(unsigned short u) {
    union { unsigned int i; float f; } v; v.i = ((unsigned int)u) << 16;
    return v.f;
}

// W1 source row for permuted k (or -1 for zero-pad)
__device__ __forceinline__ int w1_src_row(int k) {
    if (k < KMAIN) return (k >> 8) * 257 + (k & 255);   // i*257 + j
    int i = k - KMAIN;
    return (i < 257) ? (i * 257 + 256) : -1;             // (i, j=256) column
}

// ---------------------------------------------------------------------------
// Merged prep: W1t (permuted transpose+cvt), W2t (transpose+cvt),
// a_tab [2048][320] bf16, c_tab [2048][256] bf16.  One launch.
// ---------------------------------------------------------------------------
__global__ __launch_bounds__(256) void prep_kernel(
        const float* __restrict__ inp1, const float* __restrict__ inp2,
        const float* __restrict__ W1, const float* __restrict__ W2,
        unsigned short* __restrict__ W1t, unsigned short* __restrict__ W2t,
        unsigned short* __restrict__ a_tab, unsigned short* __restrict__ c_tab) {
    __shared__ float T[64][65];
    int b = blockIdx.x;
    int t = threadIdx.x;

    if (b < 8264 + 64) {
        const float* src; unsigned short* dst; int k0, n0, Kpad; bool perm;
        if (b < 8264) {
            int kt = b % 1033, nt = b / 1033;
            src = W1; dst = W1t; k0 = kt * 64; n0 = nt * 64; Kpad = KPAD; perm = true;
        } else {
            int bb = b - 8264;
            int kt = bb & 7, nt = bb >> 3;
            src = W2; dst = W2t; k0 = kt * 64; n0 = nt * 64; Kpad = 512; perm = false;
        }
        int nn = t & 63, kk0 = t >> 6;
#pragma unroll
        for (int it = 0; it < 16; ++it) {
            int kk = it * 4 + kk0;
            int k = k0 + kk;
            int row = perm ? w1_src_row(k) : k;
            float v = (row >= 0) ? src[(long)row * NHID + n0 + nn] : 0.f;
            T[kk][nn] = v;
        }
        __syncthreads();
#pragma unroll
        for (int it = 0; it < 2; ++it) {
            int idx = it * 256 + t;
            int nl = idx >> 3, ch = idx & 7;
            short8 o;
#pragma unroll
            for (int e = 0; e < 8; ++e) o[e] = (short)f2bf(T[ch * 8 + e][nl]);
            *reinterpret_cast<short8*>(&dst[(long)(n0 + nl) * Kpad + k0 + ch * 8]) = o;
        }
    } else {
        int r0 = (b - 8328) * 32;
        for (int idx = t; idx < 32 * (AW / 8); idx += 256) {
            int r = idx / 40, ch = idx - r * 40;
            int m = r0 + r;
            short8 o;
#pragma unroll
            for (int e = 0; e < 8; ++e) {
                int i = ch * 8 + e;
                float v = (i < 256) ? inp1[m * 256 + i] : (i == 256 ? 1.0f : 0.0f);
                o[e] = (short)f2bf(v);
            }
            *reinterpret_cast<short8*>(&a_tab[m * AW + ch * 8]) = o;
        }
        for (int idx = t; idx < 32 * (CW / 8); idx += 256) {
            int r = idx >> 5, ch = idx & 31;
            int m = r0 + r;
            short8 o;
#pragma unroll
            for (int e = 0; e < 8; ++e) o[e] = (short)f2bf(inp2[m * 256 + ch * 8 + e]);
            *reinterpret_cast<short8*>(&c_tab[m * CW + ch * 8]) = o;
        }
    }
}

// ---------------------------------------------------------------------------
// Stage a [128 rows][64 k] bf16 tile into LDS via global_load_lds (16B),
// XOR swizzle via permuted per-lane source chunk.  4 VMEM instrs per wave.
// ---------------------------------------------------------------------------
__device__ __forceinline__ void stage_tile128(const unsigned short* __restrict__ g,
        long row0, long k0, long ld, unsigned short* lds) {
    int t = threadIdx.x;
    int wave = t >> 6, lane = t & 63;
    int rl = lane >> 3;
    int ch = (lane & 7) ^ rl;
    const unsigned short* src0 = g + (row0 + wave * 8 + rl) * ld + k0 + ch * 8;
#pragma unroll
    for (int r = 0; r < 4; ++r) {
        const unsigned short* src = src0 + (long)r * 32 * ld;
        unsigned short* dst = lds + (r * 32 + wave * 8) * 64;   // wave-uniform
        __builtin_amdgcn_global_load_lds((const AS1 unsigned int*)src,
                                         (AS3 unsigned int*)dst, 16, 0, 0);
    }
}

// Fragment read: logical (rowbase+(lane&15), k = kofs + (lane>>4)*8 .. +8)
__device__ __forceinline__ short8 read_frag(const unsigned short* lds,
        int rowbase, int kofs, int lane) {
    int row = rowbase + (lane & 15);
    int chunkL = (kofs >> 3) + (lane >> 4);
    int sw = chunkL ^ (row & 7);
    return *reinterpret_cast<const short8*>(&lds[row * 64 + sw * 8]);
}

__device__ __forceinline__ short8 genA(float av, short8 c8) {
    short8 o;
#pragma unroll
    for (int e = 0; e < 8; ++e)
        o[e] = (short)f2bf_fast(av * bf2f((unsigned short)c8[e]));
    return o;
}

// ---------------------------------------------------------------------------
// GEMM1: depth-3 pipelined, counted vmcnt (never 0 in steady state).
// A built in registers from per-lane c-chunk cache + LDS a-window (no VMEM
// in the steady-state loop except the 4 global_load_lds of B staging).
// 4 waves; wave wv owns rows [m0+wv*32,+32) x 128 cols (acc 2x8).
// grid = 16(M) * 4(N) * 8(S) = 512 blocks = 2/CU.  Split 7 also runs the
// 9 leftover steps (i=256 rows + j=256 tail column).
// ---------------------------------------------------------------------------
__global__ __launch_bounds__(256, 2) void gemm1_kernel(
        const unsigned short* __restrict__ a_tab,
        const unsigned short* __restrict__ c_tab,
        const unsigned short* __restrict__ W1t, float* __restrict__ hacc) {
    __shared__ __align__(16) unsigned short B_s[3 * 128 * 64];   // 48 KB ring
    __shared__ __align__(16) unsigned short a_lds[128 * 40];     // 10 KB window

    int bid = (blockIdx.x & 7) * 64 + (blockIdx.x >> 3);   // XCD swizzle, 512=8*64
    int m0 = (bid & 15) * 128;
    int n0 = ((bid >> 4) & 3) * 128;
    int s  = bid >> 6;
    int st0 = s * 128;
    int stLast = st0 + 127;

    int lane = threadIdx.x & 63;
    int wv = threadIdx.x >> 6;
    int lrow = wv * 32 + (lane & 15);      // local fm=0 row
    int rowA0g = m0 + lrow;
    int rowA1g = rowA0g + 16;
    int kq = (lane >> 4) * 8;

    // ---- per-lane c-chunk cache: cc[r][q] = c_tab[row_r][kq + 32q .. +8) ----
    short8 cc0[8], cc1[8];
#pragma unroll
    for (int q = 0; q < 8; ++q) {
        cc0[q] = *reinterpret_cast<const short8*>(&c_tab[rowA0g * CW + kq + q * 32]);
        cc1[q] = *reinterpret_cast<const short8*>(&c_tab[rowA1g * CW + kq + q * 32]);
    }
    // ---- a-window -> LDS: rows m0..m0+128, i in [32s, 32s+32) ----
    for (int u = threadIdx.x; u < 512; u += 256) {
        int r = u >> 2, chk = u & 3;
        short8 v = *reinterpret_cast<const short8*>(&a_tab[(m0 + r) * AW + s * 32 + chk * 8]);
        *reinterpret_cast<short8*>(&a_lds[r * 40 + chk * 8]) = v;
    }

    f32x4 acc[2][8];
#pragma unroll
    for (int a = 0; a < 2; ++a)
#pragma unroll
        for (int b = 0; b < 8; ++b) acc[a][b] = (f32x4){0.f, 0.f, 0.f, 0.f};

    // ---- prologue: stage st0, st0+1; full drain (also publishes a_lds) ----
    stage_tile128(W1t, n0, (long)st0 * 64, KPAD, B_s);
    stage_tile128(W1t, n0, (long)(st0 + 1) * 64, KPAD, B_s + 8192);
    __syncthreads();

    int cur = 0;
    for (int g = 0; g < 32; ++g) {
        float av0 = bf2f(a_lds[lrow * 40 + g]);
        float av1 = bf2f(a_lds[(lrow + 16) * 40 + g]);
#pragma unroll
        for (int p = 0; p < 4; ++p) {
            int st = st0 + g * 4 + p;
            if (st == stLast) asm volatile("s_waitcnt vmcnt(0)" ::: "memory");
            else              asm volatile("s_waitcnt vmcnt(4)" ::: "memory");
            __builtin_amdgcn_s_barrier();
            __builtin_amdgcn_sched_barrier(0);
            if (st + 2 <= stLast) {
                int nb = cur + 2; if (nb >= 3) nb -= 3;
                stage_tile128(W1t, n0, (long)(st + 2) * 64, KPAD, B_s + nb * 8192);
            }
            // A fragments: pure VALU (chunk indices compile-time via unroll)
            short8 a0k0 = genA(av0, cc0[2 * p]);
            short8 a1k0 = genA(av1, cc1[2 * p]);
            short8 a0k1 = genA(av0, cc0[2 * p + 1]);
            short8 a1k1 = genA(av1, cc1[2 * p + 1]);
            const unsigned short* bb = B_s + cur * 8192;
            __builtin_amdgcn_s_setprio(1);
#pragma unroll
            for (int kk = 0; kk < 2; ++kk) {
                short8 aA = kk ? a0k1 : a0k0;
                short8 aB = kk ? a1k1 : a1k0;
#pragma unroll
                for (int fn = 0; fn < 8; ++fn) {
                    short8 bF = read_frag(bb, fn * 16, kk * 32, lane);
                    acc[0][fn] = __builtin_amdgcn_mfma_f32_16x16x32_bf16(
                        aA, bF, acc[0][fn], 0, 0, 0);
                    acc[1][fn] = __builtin_amdgcn_mfma_f32_16x16x32_bf16(
                        aB, bF, acc[1][fn], 0, 0, 0);
                }
            }
            __builtin_amdgcn_s_setprio(0);
            cur = (cur == 2) ? 0 : cur + 1;
        }
    }

    // ---- split 7 appends the 9 leftover steps (sloppy loop, hidden) ----
    if (s == 7) {
#pragma unroll
        for (int p = 0; p < 4; ++p) {       // st = 1024+p: i=256 row, a==1
            __syncthreads();
            stage_tile128(W1t, n0, (long)(1024 + p) * 64, KPAD, B_s);
            __syncthreads();
#pragma unroll
            for (int kk = 0; kk < 2; ++kk) {
                short8 aA = kk ? cc0[2 * p + 1] : cc0[2 * p];
                short8 aB = kk ? cc1[2 * p + 1] : cc1[2 * p];
#pragma unroll
                for (int fn = 0; fn < 8; ++fn) {
                    short8 bF = read_frag(B_s, fn * 16, kk * 32, lane);
                    acc[0][fn] = __builtin_amdgcn_mfma_f32_16x16x32_bf16(
                        aA, bF, acc[0][fn], 0, 0, 0);
                    acc[1][fn] = __builtin_amdgcn_mfma_f32_16x16x32_bf16(
                        aB, bF, acc[1][fn], 0, 0, 0);
                }
            }
        }
        for (int st = 1028; st < 1033; ++st) {   // tail: fusion col = a(m,i)
            __syncthreads();
            stage_tile128(W1t, n0, (long)st * 64, KPAD, B_s);
            int koff = (st - 1028) * 64 + kq;
            short8 t00 = *reinterpret_cast<const short8*>(&a_tab[rowA0g * AW + koff]);
            short8 t01 = *reinterpret_cast<const short8*>(&a_tab[rowA0g * AW + koff + 32]);
            short8 t10 = *reinterpret_cast<const short8*>(&a_tab[rowA1g * AW + koff]);
            short8 t11 = *reinterpret_cast<const short8*>(&a_tab[rowA1g * AW + koff + 32]);
            __syncthreads();
#pragma unroll
            for (int kk = 0; kk < 2; ++kk) {
                short8 aA = kk ? t01 : t00;
                short8 aB = kk ? t11 : t10;
#pragma unroll
                for (int fn = 0; fn < 8; ++fn) {
                    short8 bF = read_frag(B_s, fn * 16, kk * 32, lane);
                    acc[0][fn] = __builtin_amdgcn_mfma_f32_16x16x32_bf16(
                        aA, bF, acc[0][fn], 0, 0, 0);
                    acc[1][fn] = __builtin_amdgcn_mfma_f32_16x16x32_bf16(
                        aB, bF, acc[1][fn], 0, 0, 0);
                }
            }
        }
    }

    // ---- epilogue: atomic split-K accumulate into f32 hacc ----
    int cl = lane & 15;
    int r4 = (lane >> 4) * 4;
#pragma unroll
    for (int fm = 0; fm < 2; ++fm)
#pragma unroll
        for (int fn = 0; fn < 8; ++fn)
#pragma unroll
            for (int r = 0; r < 4; ++r) {
                int row = m0 + wv * 32 + fm * 16 + r4 + r;
                int col = n0 + fn * 16 + cl;
                atomicAdd(&hacc[row * NHID + col], acc[fm][fn][r]);
            }
}

// h = bf16(relu(hacc + b1))
__global__ __launch_bounds__(256) void bias_relu_h_kernel(
        const float* __restrict__ hacc, const float* __restrict__ b1,
        unsigned short* __restrict__ h) {
    int idx = blockIdx.x * 256 + threadIdx.x;
    f32x4 v = ((const f32x4*)hacc)[idx];
    int col = (idx & 127) << 2;
    f32x4 bb = *(const f32x4*)(b1 + col);
    short4v o;
#pragma unroll
    for (int e = 0; e < 4; ++e) {
        float x = v[e] + bb[e];
        x = fmaxf(x, 0.f);
        o[e] = (short)f2bf(x);
    }
    ((short4v*)h)[idx] = o;
}

// ---------------------------------------------------------------------------
// GEMM2: out = relu(h @ W2 + b2).  M=2048,N=512,K=512.  grid 16x4.
// ---------------------------------------------------------------------------
__global__ __launch_bounds__(256) void gemm2_kernel(
        const unsigned short* __restrict__ h, const unsigned short* __restrict__ W2t,
        const float* __restrict__ b2, float* __restrict__ out) {
    __shared__ unsigned short A_s[128 * 64];
    __shared__ unsigned short B_s[128 * 64];
    int m0 = (blockIdx.x >> 2) * 128;
    int n0 = (blockIdx.x & 3) * 128;
    int lane = threadIdx.x & 63;
    int wv = threadIdx.x >> 6;
    int wm = (wv >> 1) * 64;
    int wn = (wv & 1) * 64;

    f32x4 acc[4][4];
#pragma unroll
    for (int a = 0; a < 4; ++a)
#pragma unroll
        for (int b = 0; b < 4; ++b) acc[a][b] = (f32x4){0.f, 0.f, 0.f, 0.f};

    for (int st = 0; st < 8; ++st) {
        int kbase = st * 64;
        __syncthreads();
        stage_tile128(h,   m0, kbase, NHID, A_s);
        stage_tile128(W2t, n0, kbase, NHID, B_s);
        __syncthreads();
#pragma unroll
        for (int kk = 0; kk < 2; ++kk) {
            short8 aF[4], bF[4];
#pragma unroll
            for (int fm = 0; fm < 4; ++fm) aF[fm] = read_frag(A_s, wm + fm * 16, kk * 32, lane);
#pragma unroll
            for (int fn = 0; fn < 4; ++fn) bF[fn] = read_frag(B_s, wn + fn * 16, kk * 32, lane);
#pragma unroll
            for (int fm = 0; fm < 4; ++fm)
#pragma unroll
                for (int fn = 0; fn < 4; ++fn)
                    acc[fm][fn] = __builtin_amdgcn_mfma_f32_16x16x32_bf16(
                        aF[fm], bF[fn], acc[fm][fn], 0, 0, 0);
        }
    }
    int cl = lane & 15;
    int r4 = (lane >> 4) * 4;
#pragma unroll
    for (int fm = 0; fm < 4; ++fm)
#pragma unroll
        for (int fn = 0; fn < 4; ++fn)
#pragma unroll
            for (int r = 0; r < 4; ++r) {
                int row = m0 + wm + fm * 16 + r4 + r;
                int col = n0 + wn + fn * 16 + cl;
                float x = acc[fm][fn][r] + b2[col];
                out[row * NHID + col] = fmaxf(x, 0.f);
            }
}

extern "C" void kernel_launch(void* const* d_in, const int* in_sizes, int n_in,
                              void* d_out, int out_size, void* d_ws, size_t ws_size,
                              hipStream_t stream) {
    const float* inp1 = (const float*)d_in[0];
    const float* inp2 = (const float*)d_in[1];
    const float* W1   = (const float*)d_in[2];
    const float* b1   = (const float*)d_in[3];
    const float* W2   = (const float*)d_in[4];
    const float* b2   = (const float*)d_in[5];
    float* out = (float*)d_out;

    // workspace layout (~72.5 MB)
    size_t off = 0;
    auto alloc = [&](size_t bytes) {
        void* p = (char*)d_ws + off;
        off += (bytes + 255) & ~(size_t)255;
        return p;
    };
    unsigned short* W1t   = (unsigned short*)alloc((size_t)NHID * KPAD * 2);
    unsigned short* W2t   = (unsigned short*)alloc((size_t)NHID * NHID * 2);
    unsigned short* h     = (unsigned short*)alloc((size_t)BATCH * NHID * 2);
    unsigned short* a_tab = (unsigned short*)alloc((size_t)BATCH * AW * 2);
    unsigned short* c_tab = (unsigned short*)alloc((size_t)BATCH * CW * 2);
    (void)ws_size; (void)in_sizes; (void)n_in; (void)out_size;

    // d_out doubles as the f32 split-K accumulator for h_pre
    hipMemsetAsync(d_out, 0, (size_t)BATCH * NHID * 4, stream);

    prep_kernel<<<8264 + 64 + 64, 256, 0, stream>>>(inp1, inp2, W1, W2,
                                                    W1t, W2t, a_tab, c_tab);

    gemm1_kernel<<<16 * 4 * SPLITS, 256, 0, stream>>>(a_tab, c_tab, W1t, (float*)d_out);
    bias_relu_h_kernel<<<(BATCH * NHID / 4) / 256, 256, 0, stream>>>((const float*)d_out, b1, h);
    gemm2_kernel<<<64, 256, 0, stream>>>(h, W2t, b2, out);
}

// Round 8
// 209.298 us; speedup vs baseline: 1.5101x; 1.1140x over previous
//
#include <hip/hip_runtime.h>
#include <hip/hip_bf16.h>
#include <stdint.h>

// Shapes (fixed by the problem)
#define BATCH 2048
#define NHID  512
#define KMAIN 65792          // 257*256 = 1028*64  (k = i*256 + j, j<256)
#define KPAD  66112          // KMAIN + 320 = 1033*64 (tail: k-KMAIN = i, j=256 col)
#define NSTEP 1033
#define SPLITS 8             // 8 main splits x 128 steps = steps [0,1024)
#define AW 320               // a_tab row width (256 vals, 1.0 at 256, zeros to 320)
#define CW 256               // c_tab row width

typedef __attribute__((ext_vector_type(8))) short short8;
typedef __attribute__((ext_vector_type(4))) short short4v;
typedef __attribute__((ext_vector_type(4))) float f32x4;

#define AS1 __attribute__((address_space(1)))
#define AS3 __attribute__((address_space(3)))

__device__ __forceinline__ unsigned short f2bf(float f) {
    union { float f; unsigned int u; } v; v.f = f;
    unsigned int r = v.u + 0x7FFFu + ((v.u >> 16) & 1u);
    return (unsigned short)(r >> 16);
}
__device__ __forceinline__ float bf2f(unsigned short u) {
    union { unsigned int i; float f; } v; v.i = ((unsigned int)u) << 16;
    return v.f;
}

// W1 source row for permuted k (or -1 for zero-pad)
__device__ __forceinline__ int w1_src_row(int k) {
    if (k < KMAIN) return (k >> 8) * 257 + (k & 255);   // i*257 + j
    int i = k - KMAIN;
    return (i < 257) ? (i * 257 + 256) : -1;             // (i, j=256) column
}

// ---------------------------------------------------------------------------
// Merged prep: W1t (permuted transpose+cvt), W2t (transpose+cvt),
// a_tab [2048][320] bf16, c_tab [2048][256] bf16.  One launch.
// ---------------------------------------------------------------------------
__global__ __launch_bounds__(256) void prep_kernel(
        const float* __restrict__ inp1, const float* __restrict__ inp2,
        const float* __restrict__ W1, const float* __restrict__ W2,
        unsigned short* __restrict__ W1t, unsigned short* __restrict__ W2t,
        unsigned short* __restrict__ a_tab, unsigned short* __restrict__ c_tab) {
    __shared__ float T[64][65];
    int b = blockIdx.x;
    int t = threadIdx.x;

    if (b < 8264 + 64) {
        const float* src; unsigned short* dst; int k0, n0, Kpad; bool perm;
        if (b < 8264) {
            int kt = b % 1033, nt = b / 1033;
            src = W1; dst = W1t; k0 = kt * 64; n0 = nt * 64; Kpad = KPAD; perm = true;
        } else {
            int bb = b - 8264;
            int kt = bb & 7, nt = bb >> 3;
            src = W2; dst = W2t; k0 = kt * 64; n0 = nt * 64; Kpad = 512; perm = false;
        }
        int nn = t & 63, kk0 = t >> 6;
#pragma unroll
        for (int it = 0; it < 16; ++it) {
            int kk = it * 4 + kk0;
            int k = k0 + kk;
            int row = perm ? w1_src_row(k) : k;
            float v = (row >= 0) ? src[(long)row * NHID + n0 + nn] : 0.f;
            T[kk][nn] = v;
        }
        __syncthreads();
#pragma unroll
        for (int it = 0; it < 2; ++it) {
            int idx = it * 256 + t;
            int nl = idx >> 3, ch = idx & 7;
            short8 o;
#pragma unroll
            for (int e = 0; e < 8; ++e) o[e] = (short)f2bf(T[ch * 8 + e][nl]);
            *reinterpret_cast<short8*>(&dst[(long)(n0 + nl) * Kpad + k0 + ch * 8]) = o;
        }
    } else {
        int r0 = (b - 8328) * 32;
        for (int idx = t; idx < 32 * (AW / 8); idx += 256) {
            int r = idx / 40, ch = idx - r * 40;
            int m = r0 + r;
            short8 o;
#pragma unroll
            for (int e = 0; e < 8; ++e) {
                int i = ch * 8 + e;
                float v = (i < 256) ? inp1[m * 256 + i] : (i == 256 ? 1.0f : 0.0f);
                o[e] = (short)f2bf(v);
            }
            *reinterpret_cast<short8*>(&a_tab[m * AW + ch * 8]) = o;
        }
        for (int idx = t; idx < 32 * (CW / 8); idx += 256) {
            int r = idx >> 5, ch = idx & 31;
            int m = r0 + r;
            short8 o;
#pragma unroll
            for (int e = 0; e < 8; ++e) o[e] = (short)f2bf(inp2[m * 256 + ch * 8 + e]);
            *reinterpret_cast<short8*>(&c_tab[m * CW + ch * 8]) = o;
        }
    }
}

// ---------------------------------------------------------------------------
// Stage a [128 rows][64 k] bf16 tile into LDS via global_load_lds (16B),
// XOR swizzle via permuted per-lane source chunk.  4 VMEM instrs per wave.
// ---------------------------------------------------------------------------
__device__ __forceinline__ void stage_tile128(const unsigned short* __restrict__ g,
        long row0, long k0, long ld, unsigned short* lds) {
    int t = threadIdx.x;
    int wave = t >> 6, lane = t & 63;
    int rl = lane >> 3;
    int ch = (lane & 7) ^ rl;
    const unsigned short* src0 = g + (row0 + wave * 8 + rl) * ld + k0 + ch * 8;
#pragma unroll
    for (int r = 0; r < 4; ++r) {
        const unsigned short* src = src0 + (long)r * 32 * ld;
        unsigned short* dst = lds + (r * 32 + wave * 8) * 64;   // wave-uniform
        __builtin_amdgcn_global_load_lds((const AS1 unsigned int*)src,
                                         (AS3 unsigned int*)dst, 16, 0, 0);
    }
}

// Fragment read: logical (rowbase+(lane&15), k = kofs + (lane>>4)*8 .. +8)
__device__ __forceinline__ short8 read_frag(const unsigned short* lds,
        int rowbase, int kofs, int lane) {
    int row = rowbase + (lane & 15);
    int chunkL = (kofs >> 3) + (lane >> 4);
    int sw = chunkL ^ (row & 7);
    return *reinterpret_cast<const short8*>(&lds[row * 64 + sw * 8]);
}

// ---------------------------------------------------------------------------
// GEMM1 via the factorization  h[m,n] = sum_i a[m,i] * P_i[m,n],
//   P_i[m,n] = sum_j c[m,j] * W1t[n, i*256+j].
// Within an i-group (4 K-steps), the MFMA A-operand is the RAW c-chunk
// (register-cached) -- zero per-step A-generation.  Group result P is
// folded into acc with f32 scalars a[OUTPUT row, i]: the C/D layout puts
// rows r4+r (r4=(lane>>4)*4) in this lane, NOT the A-fragment row lane&15
// -- the fold must use a at those rows (R7 bug).
// Depth-3 pipelined B staging, counted vmcnt (never 0 in steady state).
// 4 waves; wave wv owns rows [m0+wv*32,+32) x 128 cols (acc 2x8).
// grid = 16(M) * 4(N) * 8(S) = 512 blocks = 2/CU.  Split 7 also runs the
// 9 leftover steps (i=256 rows + j=256 tail column).
// ---------------------------------------------------------------------------
__global__ __launch_bounds__(256, 2) void gemm1_kernel(
        const unsigned short* __restrict__ a_tab,
        const unsigned short* __restrict__ c_tab,
        const unsigned short* __restrict__ W1t, float* __restrict__ hacc) {
    __shared__ __align__(16) unsigned short B_s[3 * 128 * 64];   // 48 KB ring
    __shared__ __align__(16) unsigned short a_lds[128 * 40];     // 10 KB window

    int bid = (blockIdx.x & 7) * 64 + (blockIdx.x >> 3);   // XCD swizzle, 512=8*64
    int m0 = (bid & 15) * 128;
    int n0 = ((bid >> 4) & 3) * 128;
    int s  = bid >> 6;
    int st0 = s * 128;
    int stLast = st0 + 127;

    int lane = threadIdx.x & 63;
    int wv = threadIdx.x >> 6;
    int lrow = wv * 32 + (lane & 15);      // local fm=0 A-fragment row
    int rowA0g = m0 + lrow;
    int rowA1g = rowA0g + 16;
    int kq = (lane >> 4) * 8;
    int r4 = (lane >> 4) * 4;
    int abase = wv * 32 + r4;              // local OUTPUT row base (fm=0)

    // ---- per-lane c-chunk cache: cc[r][q] = c_tab[row_r][kq + 32q .. +8) ----
    short8 cc0[8], cc1[8];
#pragma unroll
    for (int q = 0; q < 8; ++q) {
        cc0[q] = *reinterpret_cast<const short8*>(&c_tab[rowA0g * CW + kq + q * 32]);
        cc1[q] = *reinterpret_cast<const short8*>(&c_tab[rowA1g * CW + kq + q * 32]);
    }
    // ---- a-window -> LDS: rows m0..m0+128, i in [32s, 32s+32) ----
    for (int u = threadIdx.x; u < 512; u += 256) {
        int r = u >> 2, chk = u & 3;
        short8 v = *reinterpret_cast<const short8*>(&a_tab[(m0 + r) * AW + s * 32 + chk * 8]);
        *reinterpret_cast<short8*>(&a_lds[r * 40 + chk * 8]) = v;
    }

    f32x4 acc[2][8];
#pragma unroll
    for (int a = 0; a < 2; ++a)
#pragma unroll
        for (int b = 0; b < 8; ++b) acc[a][b] = (f32x4){0.f, 0.f, 0.f, 0.f};

    // ---- prologue: stage st0, st0+1; full drain (also publishes a_lds) ----
    stage_tile128(W1t, n0, (long)st0 * 64, KPAD, B_s);
    stage_tile128(W1t, n0, (long)(st0 + 1) * 64, KPAD, B_s + 8192);
    __syncthreads();

    int cur = 0;
    for (int g = 0; g < 32; ++g) {
        f32x4 P[2][8];
#pragma unroll
        for (int a = 0; a < 2; ++a)
#pragma unroll
            for (int b = 0; b < 8; ++b) P[a][b] = (f32x4){0.f, 0.f, 0.f, 0.f};
#pragma unroll
        for (int p = 0; p < 4; ++p) {
            int st = st0 + g * 4 + p;
            if (st == stLast) asm volatile("s_waitcnt vmcnt(0)" ::: "memory");
            else              asm volatile("s_waitcnt vmcnt(4)" ::: "memory");
            __builtin_amdgcn_s_barrier();
            __builtin_amdgcn_sched_barrier(0);
            if (st + 2 <= stLast) {
                int nb = cur + 2; if (nb >= 3) nb -= 3;
                stage_tile128(W1t, n0, (long)(st + 2) * 64, KPAD, B_s + nb * 8192);
            }
            const unsigned short* bb = B_s + cur * 8192;
            __builtin_amdgcn_s_setprio(1);
#pragma unroll
            for (int kk = 0; kk < 2; ++kk) {
                short8 aA = cc0[2 * p + kk];       // raw c-chunk IS the A operand
                short8 aB = cc1[2 * p + kk];
#pragma unroll
                for (int fn = 0; fn < 8; ++fn) {
                    short8 bF = read_frag(bb, fn * 16, kk * 32, lane);
                    P[0][fn] = __builtin_amdgcn_mfma_f32_16x16x32_bf16(
                        aA, bF, P[0][fn], 0, 0, 0);
                    P[1][fn] = __builtin_amdgcn_mfma_f32_16x16x32_bf16(
                        aB, bF, P[1][fn], 0, 0, 0);
                }
            }
            __builtin_amdgcn_s_setprio(0);
            cur = (cur == 2) ? 0 : cur + 1;
        }
        // ---- fold the i-group into acc with a[OUTPUT row, i] (f32) ----
        float avA[4], avB[4];
#pragma unroll
        for (int r = 0; r < 4; ++r) {
            avA[r] = bf2f(a_lds[(abase + r) * 40 + g]);        // 16-lane broadcast
            avB[r] = bf2f(a_lds[(abase + 16 + r) * 40 + g]);
        }
#pragma unroll
        for (int fn = 0; fn < 8; ++fn)
#pragma unroll
            for (int r = 0; r < 4; ++r) {
                acc[0][fn][r] += avA[r] * P[0][fn][r];
                acc[1][fn][r] += avB[r] * P[1][fn][r];
            }
    }

    // ---- split 7 appends the 9 leftover steps (sloppy loop, hidden) ----
    if (s == 7) {
#pragma unroll
        for (int p = 0; p < 4; ++p) {       // st = 1024+p: i=256 row, a==1
            __syncthreads();
            stage_tile128(W1t, n0, (long)(1024 + p) * 64, KPAD, B_s);
            __syncthreads();
#pragma unroll
            for (int kk = 0; kk < 2; ++kk) {
                short8 aA = cc0[2 * p + kk];
                short8 aB = cc1[2 * p + kk];
#pragma unroll
                for (int fn = 0; fn < 8; ++fn) {
                    short8 bF = read_frag(B_s, fn * 16, kk * 32, lane);
                    acc[0][fn] = __builtin_amdgcn_mfma_f32_16x16x32_bf16(
                        aA, bF, acc[0][fn], 0, 0, 0);
                    acc[1][fn] = __builtin_amdgcn_mfma_f32_16x16x32_bf16(
                        aB, bF, acc[1][fn], 0, 0, 0);
                }
            }
        }
        for (int st = 1028; st < 1033; ++st) {   // tail: fusion col = a(m,i)
            __syncthreads();
            stage_tile128(W1t, n0, (long)st * 64, KPAD, B_s);
            int koff = (st - 1028) * 64 + kq;
            short8 t00 = *reinterpret_cast<const short8*>(&a_tab[rowA0g * AW + koff]);
            short8 t01 = *reinterpret_cast<const short8*>(&a_tab[rowA0g * AW + koff + 32]);
            short8 t10 = *reinterpret_cast<const short8*>(&a_tab[rowA1g * AW + koff]);
            short8 t11 = *reinterpret_cast<const short8*>(&a_tab[rowA1g * AW + koff + 32]);
            __syncthreads();
#pragma unroll
            for (int kk = 0; kk < 2; ++kk) {
                short8 aA = kk ? t01 : t00;
                short8 aB = kk ? t11 : t10;
#pragma unroll
                for (int fn = 0; fn < 8; ++fn) {
                    short8 bF = read_frag(B_s, fn * 16, kk * 32, lane);
                    acc[0][fn] = __builtin_amdgcn_mfma_f32_16x16x32_bf16(
                        aA, bF, acc[0][fn], 0, 0, 0);
                    acc[1][fn] = __builtin_amdgcn_mfma_f32_16x16x32_bf16(
                        aB, bF, acc[1][fn], 0, 0, 0);
                }
            }
        }
    }

    // ---- epilogue: atomic split-K accumulate into f32 hacc ----
    int cl = lane & 15;
#pragma unroll
    for (int fm = 0; fm < 2; ++fm)
#pragma unroll
        for (int fn = 0; fn < 8; ++fn)
#pragma unroll
            for (int r = 0; r < 4; ++r) {
                int row = m0 + wv * 32 + fm * 16 + r4 + r;
                int col = n0 + fn * 16 + cl;
                atomicAdd(&hacc[row * NHID + col], acc[fm][fn][r]);
            }
}

// h = bf16(relu(hacc + b1))
__global__ __launch_bounds__(256) void bias_relu_h_kernel(
        const float* __restrict__ hacc, const float* __restrict__ b1,
        unsigned short* __restrict__ h) {
    int idx = blockIdx.x * 256 + threadIdx.x;
    f32x4 v = ((const f32x4*)hacc)[idx];
    int col = (idx & 127) << 2;
    f32x4 bb = *(const f32x4*)(b1 + col);
    short4v o;
#pragma unroll
    for (int e = 0; e < 4; ++e) {
        float x = v[e] + bb[e];
        x = fmaxf(x, 0.f);
        o[e] = (short)f2bf(x);
    }
    ((short4v*)h)[idx] = o;
}

// ---------------------------------------------------------------------------
// GEMM2: out = relu(h @ W2 + b2).  M=2048,N=512,K=512.  grid 16x4.
// ---------------------------------------------------------------------------
__global__ __launch_bounds__(256) void gemm2_kernel(
        const unsigned short* __restrict__ h, const unsigned short* __restrict__ W2t,
        const float* __restrict__ b2, float* __restrict__ out) {
    __shared__ unsigned short A_s[128 * 64];
    __shared__ unsigned short B_s[128 * 64];
    int m0 = (blockIdx.x >> 2) * 128;
    int n0 = (blockIdx.x & 3) * 128;
    int lane = threadIdx.x & 63;
    int wv = threadIdx.x >> 6;
    int wm = (wv >> 1) * 64;
    int wn = (wv & 1) * 64;

    f32x4 acc[4][4];
#pragma unroll
    for (int a = 0; a < 4; ++a)
#pragma unroll
        for (int b = 0; b < 4; ++b) acc[a][b] = (f32x4){0.f, 0.f, 0.f, 0.f};

    for (int st = 0; st < 8; ++st) {
        int kbase = st * 64;
        __syncthreads();
        stage_tile128(h,   m0, kbase, NHID, A_s);
        stage_tile128(W2t, n0, kbase, NHID, B_s);
        __syncthreads();
#pragma unroll
        for (int kk = 0; kk < 2; ++kk) {
            short8 aF[4], bF[4];
#pragma unroll
            for (int fm = 0; fm < 4; ++fm) aF[fm] = read_frag(A_s, wm + fm * 16, kk * 32, lane);
#pragma unroll
            for (int fn = 0; fn < 4; ++fn) bF[fn] = read_frag(B_s, wn + fn * 16, kk * 32, lane);
#pragma unroll
            for (int fm = 0; fm < 4; ++fm)
#pragma unroll
                for (int fn = 0; fn < 4; ++fn)
                    acc[fm][fn] = __builtin_amdgcn_mfma_f32_16x16x32_bf16(
                        aF[fm], bF[fn], acc[fm][fn], 0, 0, 0);
        }
    }
    int cl = lane & 15;
    int r4 = (lane >> 4) * 4;
#pragma unroll
    for (int fm = 0; fm < 4; ++fm)
#pragma unroll
        for (int fn = 0; fn < 4; ++fn)
#pragma unroll
            for (int r = 0; r < 4; ++r) {
                int row = m0 + wm + fm * 16 + r4 + r;
                int col = n0 + wn + fn * 16 + cl;
                float x = acc[fm][fn][r] + b2[col];
                out[row * NHID + col] = fmaxf(x, 0.f);
            }
}

extern "C" void kernel_launch(void* const* d_in, const int* in_sizes, int n_in,
                              void* d_out, int out_size, void* d_ws, size_t ws_size,
                              hipStream_t stream) {
    const float* inp1 = (const float*)d_in[0];
    const float* inp2 = (const float*)d_in[1];
    const float* W1   = (const float*)d_in[2];
    const float* b1   = (const float*)d_in[3];
    const float* W2   = (const float*)d_in[4];
    const float* b2   = (const float*)d_in[5];
    float* out = (float*)d_out;

    // workspace layout (~72.5 MB)
    size_t off = 0;
    auto alloc = [&](size_t bytes) {
        void* p = (char*)d_ws + off;
        off += (bytes + 255) & ~(size_t)255;
        return p;
    };
    unsigned short* W1t   = (unsigned short*)alloc((size_t)NHID * KPAD * 2);
    unsigned short* W2t   = (unsigned short*)alloc((size_t)NHID * NHID * 2);
    unsigned short* h     = (unsigned short*)alloc((size_t)BATCH * NHID * 2);
    unsigned short* a_tab = (unsigned short*)alloc((size_t)BATCH * AW * 2);
    unsigned short* c_tab = (unsigned short*)alloc((size_t)BATCH * CW * 2);
    (void)ws_size; (void)in_sizes; (void)n_in; (void)out_size;

    // d_out doubles as the f32 split-K accumulator for h_pre
    hipMemsetAsync(d_out, 0, (size_t)BATCH * NHID * 4, stream);

    prep_kernel<<<8264 + 64 + 64, 256, 0, stream>>>(inp1, inp2, W1, W2,
                                                    W1t, W2t, a_tab, c_tab);

    gemm1_kernel<<<16 * 4 * SPLITS, 256, 0, stream>>>(a_tab, c_tab, W1t, (float*)d_out);
    bias_relu_h_kernel<<<(BATCH * NHID / 4) / 256, 256, 0, stream>>>((const float*)d_out, b1, h);
    gemm2_kernel<<<64, 256, 0, stream>>>(h, W2t, b2, out);
}